// Round 7
// baseline (104.315 us; speedup 1.0000x reference)
//
#include <hip/hip_runtime.h>
#include <math.h>

// Sampler: temperature 0.8, top-k (k=50 input), top-p 0.9, inverse-CDF
// multinomial. B=128 rows, V=128000, fp32 logits -> int32 ids.
//
// R7: one kernel, one block/row, 1024 thr. Same selection logic as the
// absmax-0 R6 kernel, but the ENTIRE tail is block-parallel:
//  - scan: 16 float4 in flight/thread; candidates (y >= 11.2, x >= 14)
//    pushed via wave-aggregated ballot + 1 LDS atomic per wave.
//  - two-tier filter (x >= 16 when that count >= k) -> M ~ 88.
//  - rank sort (x desc, idx asc == jnp.argsort(-x)), 1 elem/thread.
//  - tail: shuffle block-reductions (sum1/sum2), shuffle inclusive scans
//    (top-p cdf, sampling cdf), ballot counts (kth ties, top-p cut L,
//    CDF crossing). Monotone-cdf identities replace serial early-break
//    loops; fp32 reassociation is safe (decision margins >> rounding).
//  - fallback (overflow / count < k): exact kth via binary search on float
//    key bits + rescan. Never fires on this data.

#define MSORT 1024

__device__ __forceinline__ unsigned fkey(float y) {
    unsigned b = __float_as_uint(y);
    return (b & 0x80000000u) ? ~b : (b | 0x80000000u);  // y asc -> key asc
}

// block-wide sum over 1024 threads; wpart = shared float[16]; ends synced
__device__ __forceinline__ float block_sum(float v, int tid, float* wpart) {
#pragma unroll
    for (int off = 32; off > 0; off >>= 1) v += __shfl_down(v, off, 64);
    if ((tid & 63) == 0) wpart[tid >> 6] = v;
    __syncthreads();
    if (tid < 64) {
        float s = (tid < 16) ? wpart[tid] : 0.0f;
#pragma unroll
        for (int off = 8; off > 0; off >>= 1) s += __shfl_down(s, off, 64);
        if (tid == 0) wpart[0] = s;
    }
    __syncthreads();
    float s = wpart[0];
    __syncthreads();           // wpart reusable after return
    return s;
}

// in-place block inclusive scan of arr[0..n), n <= 1024; ends synced
__device__ __forceinline__ void incl_scan(float* arr, int n, int tid, float* wpart) {
    float v = (tid < n) ? arr[tid] : 0.0f;
#pragma unroll
    for (int off = 1; off < 64; off <<= 1) {
        float o = __shfl_up(v, off, 64);
        if ((tid & 63) >= off) v += o;
    }
    if ((tid & 63) == 63) wpart[tid >> 6] = v;
    __syncthreads();
    if (tid < 64) {
        float w = (tid < 16) ? wpart[tid] : 0.0f;
#pragma unroll
        for (int off = 1; off < 16; off <<= 1) {
            float o = __shfl_up(w, off, 64);
            if (tid >= off) w += o;
        }
        if (tid < 16) wpart[tid] = w;
    }
    __syncthreads();
    const int wv = tid >> 6;
    const float base = (wv > 0) ? wpart[wv - 1] : 0.0f;
    if (tid < n) arr[tid] = v + base;
    __syncthreads();
}

__global__ __launch_bounds__(1024)
void sampler_kernel(const float* __restrict__ logits,
                    const float* __restrict__ uvec,
                    const int* __restrict__ topk_p,
                    int* __restrict__ out, int V)
{
    constexpr float YTH  = 11.2f;   // candidate threshold in y-space (x = 14)
    constexpr float TEMP = 0.8f;
    constexpr float TOPP = 0.9f;
    constexpr float XTH2 = 16.0f;   // two-tier threshold in x-space (y = 12.8)

    __shared__ float gv[MSORT];     // candidates x  -> later sorted values
    __shared__ int   gi[MSORT];     // candidate idx -> later sorted indices
    __shared__ float cv[MSORT];     // compacted x   -> later se = exp(x-max)
    __shared__ int   cidx[MSORT];   // compacted idx -> later vocab-order idx
    __shared__ float sq[MSORT];     // top-p cdf -> final probs / sampling cdf
    __shared__ float wpart[16];
    __shared__ float kth_sh;
    __shared__ int   lcnt, hi_cnt, cpos, scount, cnt_sh, M_sh, tie_cnt, L_cnt, ans_sh;

    const int tid  = threadIdx.x;
    const int lane = tid & 63;
    const int row  = blockIdx.x;
    const int nth  = blockDim.x;    // 1024

    if (tid == 0) { lcnt = 0; hi_cnt = 0; cpos = 0; scount = 0;
                    tie_cnt = 0; L_cnt = 0; ans_sh = V; }
    __syncthreads();

    const float* rowp = logits + (size_t)row * (size_t)V;
    const float4* rp4 = (const float4*)rowp;
    const int n4 = V >> 2;

    // -------- scan: 16 float4 in flight; wave-aggregated candidate push ------
    for (int cb = 0; cb < n4; cb += 16 * 1024) {
        float4 vals[16];
        const int base = cb + tid;
#pragma unroll
        for (int j = 0; j < 16; ++j) {
            int i = base + j * 1024;
            vals[j] = (i < n4) ? rp4[i]
                               : make_float4(-1e30f, -1e30f, -1e30f, -1e30f);
        }
#pragma unroll
        for (int j = 0; j < 16; ++j) {
            int i = base + j * 1024;
            float ys[4] = {vals[j].x, vals[j].y, vals[j].z, vals[j].w};
#pragma unroll
            for (int c = 0; c < 4; ++c) {
                float y = ys[c];
                bool pred = (y >= YTH);
                unsigned long long bm = __ballot(pred);
                if (bm) {
                    int fl = (int)__ffsll(bm) - 1;
                    int bs = 0;
                    if (pred && lane == fl) bs = atomicAdd(&lcnt, (int)__popcll(bm));
                    bs = __shfl(bs, fl, 64);
                    if (pred) {
                        int p = bs + (int)__popcll(bm & ((1ULL << lane) - 1ULL));
                        if (p < MSORT) { gv[p] = y / TEMP; gi[p] = i * 4 + c; }
                    }
                }
            }
        }
    }
    for (int i = (n4 << 2) + tid; i < V; i += nth) {      // tail if V % 4 != 0
        float y = rowp[i];
        if (y >= YTH) {
            int p = atomicAdd(&lcnt, 1);
            if (p < MSORT) { gv[p] = y / TEMP; gi[p] = i; }
        }
    }
    __syncthreads();

    const int k_in = *topk_p;
    const int M_all = min(lcnt, MSORT);
    int M;

    if (lcnt <= MSORT && M_all >= k_in) {
        // ---- two-tier count ----
        {
            bool pred = (tid < M_all) && (gv[tid] >= XTH2);
            unsigned long long bm = __ballot(pred);
            if (lane == 0 && bm) atomicAdd(&hi_cnt, (int)__popcll(bm));
        }
        __syncthreads();
        // ---- compact, wave-aggregated ----
        const float thr = (hi_cnt >= k_in) ? XTH2 : -1e38f;
        {
            bool pred = (tid < M_all) && (gv[tid] >= thr);
            unsigned long long bm = __ballot(pred);
            if (bm) {
                int fl = (int)__ffsll(bm) - 1;
                int bs = 0;
                if (pred && lane == fl) bs = atomicAdd(&cpos, (int)__popcll(bm));
                bs = __shfl(bs, fl, 64);
                if (pred) {
                    int p = bs + (int)__popcll(bm & ((1ULL << lane) - 1ULL));
                    cv[p] = gv[tid]; cidx[p] = gi[tid];
                }
            }
        }
        __syncthreads();
        M = cpos;
    } else {
        // ---- exact fallback: kth value via binary search on float key bits ----
        unsigned lo = 0;
        for (int bit = 31; bit >= 0; --bit) {
            unsigned t = lo | (1u << bit);
            int local = 0;
            for (int i = tid; i < V; i += nth) local += (fkey(rowp[i]) >= t);
            if (tid == 0) cnt_sh = 0;
            __syncthreads();
            atomicAdd(&cnt_sh, local);
            __syncthreads();
            if (cnt_sh >= k_in) lo = t;
            __syncthreads();
        }
        for (int i = tid; i < V; i += nth) {
            float y = rowp[i];
            if (fkey(y) >= lo) {
                int p = atomicAdd(&scount, 1);
                if (p < MSORT) { cv[p] = y / TEMP; cidx[p] = i; }
            }
        }
        __syncthreads();
        M = min(scount, MSORT);
    }
    if (tid == 0) M_sh = M;
    __syncthreads();
    M = M_sh;

    // ---- pad to multiple of 4 with sentinels (branch-free unrolled loop) ----
    const int Mpad = (M + 3) & ~3;
    for (int t = M + tid; t < Mpad; t += nth) { cv[t] = -1e38f; cidx[t] = 0x7fffffff; }
    __syncthreads();

    // ---- rank sort: x desc, tie idx asc (== argsort(-x)); 1 elem/thread ----
    if (tid < M) {
        const float v = cv[tid]; const int ix = cidx[tid];
        int r = 0;
        for (int j = 0; j < Mpad; j += 4) {
            float v0 = cv[j],     v1 = cv[j + 1];
            float v2 = cv[j + 2], v3 = cv[j + 3];
            int   i0 = cidx[j],     i1 = cidx[j + 1];
            int   i2 = cidx[j + 2], i3 = cidx[j + 3];
            r += (v0 > v || (v0 == v && i0 < ix));
            r += (v1 > v || (v1 == v && i1 < ix));
            r += (v2 > v || (v2 == v && i2 < ix));
            r += (v3 > v || (v3 == v && i3 < ix));
        }
        gv[r] = v; gi[r] = ix;      // gv/gi now hold the sorted list
    }
    __syncthreads();

    // ---- parallel tail ----
    const int kk = (M > 0) ? min(max(k_in, 1), M) : 0;
    const float mm = (M > 0) ? gv[0] : 0.0f;
    if (tid < M) cv[tid] = expf(gv[tid] - mm);            // cv = se
    if (tid == 0 && M > 0) kth_sh = gv[kk - 1];
    __syncthreads();

    // ties with the kth value (sorted => ties contiguous): Kp = kk + #equal
    {
        bool f = (M > 0) && (tid >= kk) && (tid < M) && (gv[tid] == kth_sh);
        unsigned long long bm = __ballot(f);
        if (lane == 0 && bm) atomicAdd(&tie_cnt, (int)__popcll(bm));
    }
    __syncthreads();
    const int Kp = kk + tie_cnt;

    // sum1 = sum(se[0..Kp))
    const float sum1 = block_sum((tid < Kp) ? cv[tid] : 0.0f, tid, wpart);

    // top-p: Q = inclusive cdf of q = se/sum1; L = 1 + #{i in [1,Kp): Q[i-1]<=p}
    if (tid < Kp) sq[tid] = cv[tid] / sum1;
    incl_scan(sq, Kp, tid, wpart);
    {
        bool f = (tid >= 1) && (tid < Kp) && (sq[tid - 1] <= TOPP);
        unsigned long long bm = __ballot(f);
        if (lane == 0 && bm) atomicAdd(&L_cnt, (int)__popcll(bm));
    }
    __syncthreads();
    const int L = (M > 0) ? (1 + L_cnt) : 0;

    // sum2 = sum(se[0..L))
    const float sum2 = block_sum((tid < L) ? cv[tid] : 0.0f, tid, wpart);

    // reorder kept entries by vocab index: sq[r] = prob, cidx[r] = idx
    if (tid < L) {
        const int ix = gi[tid];
        int r = 0;
        for (int j = 0; j < L; ++j) r += (gi[j] < ix);
        sq[r] = cv[tid] / sum2;
        cidx[r] = ix;
    }
    __syncthreads();

    // sampling cdf + unique crossing: first i with C[i] > u
    incl_scan(sq, L, tid, wpart);
    {
        const float uu = uvec[row];
        bool f = (tid < L) && (sq[tid] > uu) && (tid == 0 || sq[tid - 1] <= uu);
        if (f) ans_sh = cidx[tid];   // unique by monotonicity
    }
    __syncthreads();
    if (tid == 0) out[row] = ans_sh;   // default V if no crossing (u >= total)
}

extern "C" void kernel_launch(void* const* d_in, const int* in_sizes, int n_in,
                              void* d_out, int out_size, void* d_ws, size_t ws_size,
                              hipStream_t stream) {
    const float* logits = (const float*)d_in[0];
    const float* u      = (const float*)d_in[1];
    const int*   topk   = (const int*)d_in[2];
    int*         out    = (int*)d_out;

    const int B = out_size;              // 128 rows
    const int V = in_sizes[0] / B;       // 128000

    sampler_kernel<<<B, 1024, 0, stream>>>(logits, u, topk, out, V);
}

// Round 8
// 102.846 us; speedup vs baseline: 1.0143x; 1.0143x over previous
//
#include <hip/hip_runtime.h>
#include <math.h>

// Sampler: temperature 0.8, top-k (k=50 input), top-p 0.9, inverse-CDF
// multinomial. B=128 rows, V=128000, fp32 logits -> int32 ids.
//
// R8: one kernel, one block/row, 1024 thr. Scan rewritten compiler-friendly:
//  - 8 NAMED float4 registers (no indexed array -> no scratch, no load-use
//    fusion), straight-line loads then uses, main loop bounds-check-free.
//  - max-of-4 pre-filter per float4 -> one rare branch per 4 elements.
//  - plain LDS-atomic candidate push (y >= 11.2, x >= 14; ~327/row).
//  - two-tier filter (x >= 16 when count >= k) -> M ~ 88, exact superset
//    of top-k + kth ties.
//  - rank sort (x desc, idx asc == jnp.argsort(-x)), 1 elem/thread.
//  - block-parallel tail (R7): shuffle reductions/scans + ballot counts;
//    monotone-cdf identities; fp32 margins >> rounding.
//  - fallback (overflow / count < k): exact kth via binary search on float
//    key bits + rescan. Never fires on this data.

#define MSORT 1024

__device__ __forceinline__ unsigned fkey(float y) {
    unsigned b = __float_as_uint(y);
    return (b & 0x80000000u) ? ~b : (b | 0x80000000u);  // y asc -> key asc
}

// block-wide sum over 1024 threads; wpart = shared float[16]; ends synced
__device__ __forceinline__ float block_sum(float v, int tid, float* wpart) {
#pragma unroll
    for (int off = 32; off > 0; off >>= 1) v += __shfl_down(v, off, 64);
    if ((tid & 63) == 0) wpart[tid >> 6] = v;
    __syncthreads();
    if (tid < 64) {
        float s = (tid < 16) ? wpart[tid] : 0.0f;
#pragma unroll
        for (int off = 8; off > 0; off >>= 1) s += __shfl_down(s, off, 64);
        if (tid == 0) wpart[0] = s;
    }
    __syncthreads();
    float s = wpart[0];
    __syncthreads();
    return s;
}

// in-place block inclusive scan of arr[0..n), n <= 1024; ends synced
__device__ __forceinline__ void incl_scan(float* arr, int n, int tid, float* wpart) {
    float v = (tid < n) ? arr[tid] : 0.0f;
#pragma unroll
    for (int off = 1; off < 64; off <<= 1) {
        float o = __shfl_up(v, off, 64);
        if ((tid & 63) >= off) v += o;
    }
    if ((tid & 63) == 63) wpart[tid >> 6] = v;
    __syncthreads();
    if (tid < 64) {
        float w = (tid < 16) ? wpart[tid] : 0.0f;
#pragma unroll
        for (int off = 1; off < 16; off <<= 1) {
            float o = __shfl_up(w, off, 64);
            if (tid >= off) w += o;
        }
        if (tid < 16) wpart[tid] = w;
    }
    __syncthreads();
    const int wv = tid >> 6;
    const float base = (wv > 0) ? wpart[wv - 1] : 0.0f;
    if (tid < n) arr[tid] = v + base;
    __syncthreads();
}

__global__ __launch_bounds__(1024)
void sampler_kernel(const float* __restrict__ logits,
                    const float* __restrict__ uvec,
                    const int* __restrict__ topk_p,
                    int* __restrict__ out, int V)
{
    constexpr float YTH  = 11.2f;   // candidate threshold in y-space (x = 14)
    constexpr float TEMP = 0.8f;
    constexpr float TOPP = 0.9f;
    constexpr float XTH2 = 16.0f;   // two-tier threshold in x-space (y = 12.8)

    __shared__ float gv[MSORT];     // candidates x  -> later sorted values
    __shared__ int   gi[MSORT];     // candidate idx -> later sorted indices
    __shared__ float cv[MSORT];     // compacted x   -> later se = exp(x-max)
    __shared__ int   cidx[MSORT];   // compacted idx -> later vocab-order idx
    __shared__ float sq[MSORT];     // top-p cdf -> final probs / sampling cdf
    __shared__ float wpart[16];
    __shared__ float kth_sh;
    __shared__ int   lcnt, hi_cnt, cpos, scount, cnt_sh, M_sh, tie_cnt, L_cnt, ans_sh;

    const int tid  = threadIdx.x;
    const int lane = tid & 63;
    const int row  = blockIdx.x;
    const int nth  = blockDim.x;    // 1024

    if (tid == 0) { lcnt = 0; hi_cnt = 0; cpos = 0; scount = 0;
                    tie_cnt = 0; L_cnt = 0; ans_sh = V; }
    __syncthreads();

    const float* rowp = logits + (size_t)row * (size_t)V;
    const float4* rp4 = (const float4*)rowp;
    const int n4 = V >> 2;

    // helper macro: max-of-4 pre-filter + rare push (i4 = float4 index)
#define SCAN4(vv, i4)                                                          \
    {                                                                          \
        float _m = fmaxf(fmaxf((vv).x, (vv).y), fmaxf((vv).z, (vv).w));        \
        if (_m >= YTH) {                                                       \
            if ((vv).x >= YTH) { int _p = atomicAdd(&lcnt, 1);                 \
                if (_p < MSORT) { gv[_p] = (vv).x / TEMP; gi[_p] = (i4)*4;   } } \
            if ((vv).y >= YTH) { int _p = atomicAdd(&lcnt, 1);                 \
                if (_p < MSORT) { gv[_p] = (vv).y / TEMP; gi[_p] = (i4)*4+1; } } \
            if ((vv).z >= YTH) { int _p = atomicAdd(&lcnt, 1);                 \
                if (_p < MSORT) { gv[_p] = (vv).z / TEMP; gi[_p] = (i4)*4+2; } } \
            if ((vv).w >= YTH) { int _p = atomicAdd(&lcnt, 1);                 \
                if (_p < MSORT) { gv[_p] = (vv).w / TEMP; gi[_p] = (i4)*4+3; } } \
        }                                                                      \
    }

    // ---- main scan: 8 named float4 in flight, no bounds checks ----
    const int DEPTH = 8;
    const int n4_main = (n4 / (DEPTH * 1024)) * (DEPTH * 1024);
    for (int base = 0; base < n4_main; base += DEPTH * 1024) {
        const int i0 = base + tid;
        float4 a0 = rp4[i0];
        float4 a1 = rp4[i0 + 1024];
        float4 a2 = rp4[i0 + 2048];
        float4 a3 = rp4[i0 + 3072];
        float4 a4 = rp4[i0 + 4096];
        float4 a5 = rp4[i0 + 5120];
        float4 a6 = rp4[i0 + 6144];
        float4 a7 = rp4[i0 + 7168];
        SCAN4(a0, i0);
        SCAN4(a1, i0 + 1024);
        SCAN4(a2, i0 + 2048);
        SCAN4(a3, i0 + 3072);
        SCAN4(a4, i0 + 4096);
        SCAN4(a5, i0 + 5120);
        SCAN4(a6, i0 + 6144);
        SCAN4(a7, i0 + 7168);
    }
    for (int i = n4_main + tid; i < n4; i += 1024) {   // remainder float4s
        float4 a = rp4[i];
        SCAN4(a, i);
    }
    for (int i = (n4 << 2) + tid; i < V; i += nth) {   // scalar tail (V%4)
        float y = rowp[i];
        if (y >= YTH) {
            int p = atomicAdd(&lcnt, 1);
            if (p < MSORT) { gv[p] = y / TEMP; gi[p] = i; }
        }
    }
#undef SCAN4
    __syncthreads();

    const int k_in = *topk_p;
    const int M_all = min(lcnt, MSORT);
    int M;

    if (lcnt <= MSORT && M_all >= k_in) {
        // ---- two-tier count ----
        {
            bool pred = (tid < M_all) && (gv[tid] >= XTH2);
            unsigned long long bm = __ballot(pred);
            if (lane == 0 && bm) atomicAdd(&hi_cnt, (int)__popcll(bm));
        }
        __syncthreads();
        // ---- compact, wave-aggregated ----
        const float thr = (hi_cnt >= k_in) ? XTH2 : -1e38f;
        {
            bool pred = (tid < M_all) && (gv[tid] >= thr);
            unsigned long long bm = __ballot(pred);
            if (bm) {
                int fl = (int)__ffsll(bm) - 1;
                int bs = 0;
                if (pred && lane == fl) bs = atomicAdd(&cpos, (int)__popcll(bm));
                bs = __shfl(bs, fl, 64);
                if (pred) {
                    int p = bs + (int)__popcll(bm & ((1ULL << lane) - 1ULL));
                    cv[p] = gv[tid]; cidx[p] = gi[tid];
                }
            }
        }
        __syncthreads();
        M = cpos;
    } else {
        // ---- exact fallback: kth value via binary search on float key bits ----
        unsigned lo = 0;
        for (int bit = 31; bit >= 0; --bit) {
            unsigned t = lo | (1u << bit);
            int local = 0;
            for (int i = tid; i < V; i += nth) local += (fkey(rowp[i]) >= t);
            if (tid == 0) cnt_sh = 0;
            __syncthreads();
            atomicAdd(&cnt_sh, local);
            __syncthreads();
            if (cnt_sh >= k_in) lo = t;
            __syncthreads();
        }
        for (int i = tid; i < V; i += nth) {
            float y = rowp[i];
            if (fkey(y) >= lo) {
                int p = atomicAdd(&scount, 1);
                if (p < MSORT) { cv[p] = y / TEMP; cidx[p] = i; }
            }
        }
        __syncthreads();
        M = min(scount, MSORT);
    }
    if (tid == 0) M_sh = M;
    __syncthreads();
    M = M_sh;

    // ---- pad to multiple of 4 with sentinels (branch-free unrolled loop) ----
    const int Mpad = (M + 3) & ~3;
    for (int t = M + tid; t < Mpad; t += nth) { cv[t] = -1e38f; cidx[t] = 0x7fffffff; }
    __syncthreads();

    // ---- rank sort: x desc, tie idx asc (== argsort(-x)); 1 elem/thread ----
    if (tid < M) {
        const float v = cv[tid]; const int ix = cidx[tid];
        int r = 0;
        for (int j = 0; j < Mpad; j += 4) {
            float v0 = cv[j],     v1 = cv[j + 1];
            float v2 = cv[j + 2], v3 = cv[j + 3];
            int   i0 = cidx[j],     i1 = cidx[j + 1];
            int   i2 = cidx[j + 2], i3 = cidx[j + 3];
            r += (v0 > v || (v0 == v && i0 < ix));
            r += (v1 > v || (v1 == v && i1 < ix));
            r += (v2 > v || (v2 == v && i2 < ix));
            r += (v3 > v || (v3 == v && i3 < ix));
        }
        gv[r] = v; gi[r] = ix;      // gv/gi now hold the sorted list
    }
    __syncthreads();

    // ---- parallel tail ----
    const int kk = (M > 0) ? min(max(k_in, 1), M) : 0;
    const float mm = (M > 0) ? gv[0] : 0.0f;
    if (tid < M) cv[tid] = expf(gv[tid] - mm);            // cv = se
    if (tid == 0 && M > 0) kth_sh = gv[kk - 1];
    __syncthreads();

    // ties with the kth value (sorted => ties contiguous): Kp = kk + #equal
    {
        bool f = (M > 0) && (tid >= kk) && (tid < M) && (gv[tid] == kth_sh);
        unsigned long long bm = __ballot(f);
        if (lane == 0 && bm) atomicAdd(&tie_cnt, (int)__popcll(bm));
    }
    __syncthreads();
    const int Kp = kk + tie_cnt;

    // sum1 = sum(se[0..Kp))
    const float sum1 = block_sum((tid < Kp) ? cv[tid] : 0.0f, tid, wpart);

    // top-p: Q = inclusive cdf of q = se/sum1; L = 1 + #{i in [1,Kp): Q[i-1]<=p}
    if (tid < Kp) sq[tid] = cv[tid] / sum1;
    incl_scan(sq, Kp, tid, wpart);
    {
        bool f = (tid >= 1) && (tid < Kp) && (sq[tid - 1] <= TOPP);
        unsigned long long bm = __ballot(f);
        if (lane == 0 && bm) atomicAdd(&L_cnt, (int)__popcll(bm));
    }
    __syncthreads();
    const int L = (M > 0) ? (1 + L_cnt) : 0;

    // sum2 = sum(se[0..L))
    const float sum2 = block_sum((tid < L) ? cv[tid] : 0.0f, tid, wpart);

    // reorder kept entries by vocab index: sq[r] = prob, cidx[r] = idx
    if (tid < L) {
        const int ix = gi[tid];
        int r = 0;
        for (int j = 0; j < L; ++j) r += (gi[j] < ix);
        sq[r] = cv[tid] / sum2;
        cidx[r] = ix;
    }
    __syncthreads();

    // sampling cdf + unique crossing: first i with C[i] > u
    incl_scan(sq, L, tid, wpart);
    {
        const float uu = uvec[row];
        bool f = (tid < L) && (sq[tid] > uu) && (tid == 0 || sq[tid - 1] <= uu);
        if (f) ans_sh = cidx[tid];   // unique by monotonicity
    }
    __syncthreads();
    if (tid == 0) out[row] = ans_sh;   // default V if no crossing (u >= total)
}

extern "C" void kernel_launch(void* const* d_in, const int* in_sizes, int n_in,
                              void* d_out, int out_size, void* d_ws, size_t ws_size,
                              hipStream_t stream) {
    const float* logits = (const float*)d_in[0];
    const float* u      = (const float*)d_in[1];
    const int*   topk   = (const int*)d_in[2];
    int*         out    = (int*)d_out;

    const int B = out_size;              // 128 rows
    const int V = in_sizes[0] / B;       // 128000

    sampler_kernel<<<B, 1024, 0, stream>>>(logits, u, topk, out, V);
}